// Round 6
// baseline (101.790 us; speedup 1.0000x reference)
//
#include <hip/hip_runtime.h>
#include <hip/hip_bf16.h>
#include <stdint.h>

// ---------------------------------------------------------------------------
// MultiHeadCrossAttention, B=8 C=512 H=W=64 nh=8 d=64.
// Index algebra (t = h*64+w, f = t*512+c):
//   n = h>>3, dd = (h&7)*8 + (w>>3), hh = (w&7)*8 + (c>>6), ww = c&63
// With e = hh&7, g = hh>>3: token j within slab (b,n): j = 8*dd + g.
// q broadcast over tokens -> scores rank-1:
//   scores[qq,kk] = qs[b][e*64+qq] * K2[b,n,g][e*64+kk]
//   qs = (guide@Wq^T + bq)*0.125 ; K2 = hrsum@Wk^T + 64*bk
//   hrsum[b,n,g,c'] = sum_{j==g mod 8} hid[b,c',n*512+j]
// attended[qq,dd] = sum_kk softmax(scores)[qq,kk] * V[e*64+kk][j(dd,g)]
//   V[c][j] = sum_c' Wv[c][c'] * hid[b][c'][n*512+j] + bv[c]
// out[b][n*64+dd][g*8+e][qq]
//
// k_fused (r6 = r5 + shfl-transpose fix): wave w == e. B (XT rows, 64KB)
// staged ONCE via global_load_lds -> single __syncthreads -> barrier-free
// K-loop (A reg-streamed from L2, depth-2 prefetch) -> pack acc to bf16
// pk[][] -> rank-1 softmax -> PV as D[m=qq][n=dd] with B-operand built by
// 4-lane shfl transpose of pk (dual-shfl + destination-side select; the
// r5 version selected in the SOURCE lane -> wrong mt for half the lanes)
// -> float4 stores. No barriers after the prologue.
// ---------------------------------------------------------------------------

typedef __attribute__((ext_vector_type(8))) short bf16x8_t;
typedef __attribute__((ext_vector_type(4))) float f32x4_t;

__device__ __forceinline__ unsigned short f2bf(float f) {
  unsigned int u = __float_as_uint(f);
  u += 0x7FFFu + ((u >> 16) & 1u);
  return (unsigned short)(u >> 16);
}

__device__ __forceinline__ void gload16(const void* g, void* lds) {
  __builtin_amdgcn_global_load_lds(
      (const __attribute__((address_space(1))) unsigned int*)g,
      (__attribute__((address_space(3))) unsigned int*)lds, 16, 0, 0);
}

// ---------------- kernel 2: transpose hid -> XT (bf16) + hrsum (fp32) -------
// blocks [0,512): transpose+hrsum. blocks [512,528): Wv fp32->bf16 convert.
__global__ __launch_bounds__(256) void k_trans(const float* __restrict__ hid,
                                               unsigned short* __restrict__ XT,
                                               float* __restrict__ hrsum,
                                               const float* __restrict__ Wv,
                                               unsigned short* __restrict__ Wvb) {
  int bid = blockIdx.x;
  int tid = threadIdx.x;
  if (bid >= 512) {
    int blk = bid - 512;
#pragma unroll
    for (int i = 0; i < 16; ++i) {
      int idx = blk * 4096 + i * 256 + tid;
      float4 v = ((const float4*)Wv)[idx];
      ushort4 o;
      o.x = f2bf(v.x); o.y = f2bf(v.y); o.z = f2bf(v.z); o.w = f2bf(v.w);
      ((ushort4*)Wvb)[idx] = o;
    }
    return;
  }
  int cb = bid & 7, n = (bid >> 3) & 7, b = bid >> 6;
  __shared__ float T[64][65];
  __shared__ float hsred[64][8];

  for (int i = tid; i < 512; i += 256) ((float*)hsred)[i] = 0.f;

  float part[4][4];
#pragma unroll
  for (int m = 0; m < 4; ++m)
#pragma unroll
    for (int i = 0; i < 4; ++i) part[m][i] = 0.f;

  const int f4 = tid & 15;
  const int r0 = tid >> 4;
  const float* srcbase = hid + (size_t)(b * 512 + cb * 64) * 4096 + n * 512;
  unsigned short* xtbase = XT + (size_t)(b * 8 + n) * 512 * 512 + cb * 64;

  for (int jc = 0; jc < 8; ++jc) {
    __syncthreads();
#pragma unroll
    for (int m = 0; m < 4; ++m) {
      int r = r0 + 16 * m;
      float4 v = *(const float4*)(srcbase + (size_t)r * 4096 + jc * 64 + f4 * 4);
      T[r][f4 * 4 + 0] = v.x;  T[r][f4 * 4 + 1] = v.y;
      T[r][f4 * 4 + 2] = v.z;  T[r][f4 * 4 + 3] = v.w;
      part[m][0] += v.x; part[m][1] += v.y; part[m][2] += v.z; part[m][3] += v.w;
    }
    __syncthreads();
#pragma unroll
    for (int p = 0; p < 2; ++p) {
      int jl = (tid >> 3) + p * 32;
      int o = tid & 7;
      unsigned short t0 = f2bf(T[o * 8 + 0][jl]);
      unsigned short t1 = f2bf(T[o * 8 + 1][jl]);
      unsigned short t2 = f2bf(T[o * 8 + 2][jl]);
      unsigned short t3 = f2bf(T[o * 8 + 3][jl]);
      unsigned short t4 = f2bf(T[o * 8 + 4][jl]);
      unsigned short t5 = f2bf(T[o * 8 + 5][jl]);
      unsigned short t6 = f2bf(T[o * 8 + 6][jl]);
      unsigned short t7 = f2bf(T[o * 8 + 7][jl]);
      uint4 pk;
      pk.x = (unsigned)t0 | ((unsigned)t1 << 16);
      pk.y = (unsigned)t2 | ((unsigned)t3 << 16);
      pk.z = (unsigned)t4 | ((unsigned)t5 << 16);
      pk.w = (unsigned)t6 | ((unsigned)t7 << 16);
      *(uint4*)(xtbase + (size_t)(jc * 64 + jl) * 512 + o * 8) = pk;
    }
  }
  __syncthreads();
  {
    int gbase = (tid & 1) * 4;
#pragma unroll
    for (int m = 0; m < 4; ++m) {
      int r = r0 + 16 * m;
#pragma unroll
      for (int i = 0; i < 4; ++i) atomicAdd(&hsred[r][gbase + i], part[m][i]);
    }
  }
  __syncthreads();
  float* hout = hrsum + (size_t)(b * 8 + n) * 8 * 512 + cb * 64;
  for (int i = tid; i < 512; i += 256) {
    int g = i >> 6, r = i & 63;
    hout[(size_t)g * 512 + r] = hsred[r][g];
  }
}

// ---------------- kernel 3: K2 = hrsum@Wk^T + 64*bk ; qs = (guide@Wq^T+bq)/8 -
__global__ __launch_bounds__(256) void k_k2(const float* __restrict__ hrsum,
                                            const float* __restrict__ Wk,
                                            const float* __restrict__ bk,
                                            const float* __restrict__ guide,
                                            const float* __restrict__ Wq,
                                            const float* __restrict__ bq,
                                            float* __restrict__ K2,
                                            float* __restrict__ qs) {
  int bid = blockIdx.x;
  int rt = bid >> 4, ct = bid & 15;
  bool isQ = (rt == 16);
  const float* A = isQ ? guide : (hrsum + (size_t)rt * 32 * 512);
  const float* Bm = isQ ? Wq : Wk;
  int arows = isQ ? 8 : 32;
  int tid = threadIdx.x;
  __shared__ float Ah[32][36];
  __shared__ float Bh[32][36];
  int r = tid >> 3, f = tid & 7;
  int oy = (tid >> 4) * 2, ox = (tid & 15) * 2;
  float a00 = 0.f, a01 = 0.f, a10 = 0.f, a11 = 0.f;

  for (int kc = 0; kc < 16; ++kc) {
    __syncthreads();
    float4 av = (r < arows) ? *(const float4*)(A + (size_t)r * 512 + kc * 32 + f * 4)
                            : make_float4(0.f, 0.f, 0.f, 0.f);
    *(float4*)(&Ah[r][f * 4]) = av;
    float4 bv = *(const float4*)(Bm + (size_t)(ct * 32 + r) * 512 + kc * 32 + f * 4);
    *(float4*)(&Bh[r][f * 4]) = bv;
    __syncthreads();
#pragma unroll
    for (int kk = 0; kk < 32; kk += 4) {
      float4 x0 = *(float4*)(&Ah[oy][kk]);
      float4 x1 = *(float4*)(&Ah[oy + 1][kk]);
      float4 y0 = *(float4*)(&Bh[ox][kk]);
      float4 y1 = *(float4*)(&Bh[ox + 1][kk]);
      a00 += x0.x * y0.x + x0.y * y0.y + x0.z * y0.z + x0.w * y0.w;
      a01 += x0.x * y1.x + x0.y * y1.y + x0.z * y1.z + x0.w * y1.w;
      a10 += x1.x * y0.x + x1.y * y0.y + x1.z * y0.z + x1.w * y0.w;
      a11 += x1.x * y1.x + x1.y * y1.y + x1.z * y1.z + x1.w * y1.w;
    }
  }
  int c0 = ct * 32 + ox;
  if (!isQ) {
    int row0 = rt * 32 + oy;
    K2[(size_t)row0 * 512 + c0]           = a00 + 64.f * bk[c0];
    K2[(size_t)row0 * 512 + c0 + 1]       = a01 + 64.f * bk[c0 + 1];
    K2[(size_t)(row0 + 1) * 512 + c0]     = a10 + 64.f * bk[c0];
    K2[(size_t)(row0 + 1) * 512 + c0 + 1] = a11 + 64.f * bk[c0 + 1];
  } else if (oy < 8) {
    const float scale = 0.125f;
    qs[(size_t)oy * 512 + c0]           = (a00 + bq[c0]) * scale;
    qs[(size_t)oy * 512 + c0 + 1]       = (a01 + bq[c0 + 1]) * scale;
    qs[(size_t)(oy + 1) * 512 + c0]     = (a10 + bq[c0]) * scale;
    qs[(size_t)(oy + 1) * 512 + c0 + 1] = (a11 + bq[c0 + 1]) * scale;
  }
}

// ---------------- kernel 4: fused V-GEMM + rank-1 softmax + PV ---------------
// grid 512 = slab(64) * g(8), XCD-grouped; 512 threads = 8 waves, wave w = e.
// LDS: B [8 kc regions][64 j][128B] = 64KB total -> 2 blocks/CU.
__global__ __launch_bounds__(512, 4) void k_fused(
    const unsigned short* __restrict__ XT, const unsigned short* __restrict__ Wvb,
    const float* __restrict__ K2, const float* __restrict__ qs,
    const float* __restrict__ bv, float* __restrict__ out) {
  // XCD-aware swizzle: XCD x gets slabs [8x, 8x+8), all 8 g's per slab.
  int p = blockIdx.x;
  int xcd = p & 7, idx = p >> 3;
  int slab = xcd * 8 + (idx & 7);
  int g = idx >> 3;
  int n = slab & 7, b = slab >> 3;

  int tid = threadIdx.x;
  int w = tid >> 6, l = tid & 63;
  int l15 = l & 15, l4 = l >> 4, lr = l >> 3, lc = l & 7;

  __shared__ __align__(16) unsigned char smem[65536];

  const unsigned swzel = (unsigned)((lc ^ lr) << 3);  // pre-swizzled src col
  const unsigned short* bsrc = XT + (size_t)slab * 512 * 512;
  const unsigned short* wbase = Wvb + (size_t)(w * 64 + l15) * 512 + l4 * 8;
  const int brow = 8 * (w * 8 + lr) + g;   // XT j-row this lane stages (dd = w*8+lr)

  // ---- stage B once: 8 x global_load_lds (16B) per thread ----
#pragma unroll
  for (int i = 0; i < 8; ++i)
    gload16(bsrc + (size_t)brow * 512 + i * 64 + swzel, smem + i * 8192 + w * 1024);

  // scalars for phase 2
  float alpha = qs[(size_t)b * 512 + w * 64 + l];              // lane = qq
  float beta  = K2[(size_t)(slab * 8 + g) * 512 + w * 64 + l]; // lane = kk
  float bvreg = bv[w * 64 + l];                                // lane = kk

  f32x4_t acc[4][4];
#pragma unroll
  for (int i = 0; i < 4; ++i)
#pragma unroll
    for (int j = 0; j < 4; ++j) acc[i][j] = (f32x4_t){0.f, 0.f, 0.f, 0.f};

  __syncthreads();   // one full drain; B resident for the rest of the kernel

  // ---- barrier-free K-loop: 16 K32-steps, A reg-streamed, depth-2 prefetch --
  bf16x8_t af[2][4];
#pragma unroll
  for (int mt = 0; mt < 4; ++mt)
    af[0][mt] = *(const bf16x8_t*)(wbase + mt * 16 * 512);

#pragma unroll
  for (int s = 0; s < 16; ++s) {
    if (s < 15) {
#pragma unroll
      for (int mt = 0; mt < 4; ++mt)
        af[(s + 1) & 1][mt] =
            *(const bf16x8_t*)(wbase + mt * 16 * 512 + (s + 1) * 32);
    }
    unsigned char* Bb = smem + (s >> 1) * 8192;
    bf16x8_t bfr[4];
#pragma unroll
    for (int nt = 0; nt < 4; ++nt) {
      unsigned row = (unsigned)(nt * 16 + l15);
      bfr[nt] = *(const bf16x8_t*)(Bb + row * 128 +
                ((unsigned)((s & 1) * 64 + l4 * 16) ^ ((row & 7) << 4)));
    }
    __builtin_amdgcn_s_setprio(1);
#pragma unroll
    for (int mt = 0; mt < 4; ++mt)
#pragma unroll
      for (int nt = 0; nt < 4; ++nt)
        acc[mt][nt] = __builtin_amdgcn_mfma_f32_16x16x32_bf16(
            af[s & 1][mt], bfr[nt], acc[mt][nt], 0, 0, 0);
    __builtin_amdgcn_s_setprio(0);
  }

  // ---- pack V + bias -> bf16 pairs in registers ----
  // acc[mt][nt] reg r: kk = mt*16 + l4*4 + r, dd = nt*16 + l15.
  uint2 pk[4][4];
#pragma unroll
  for (int mt = 0; mt < 4; ++mt) {
    float bq0 = __shfl(bvreg, mt * 16 + l4 * 4 + 0);
    float bq1 = __shfl(bvreg, mt * 16 + l4 * 4 + 1);
    float bq2 = __shfl(bvreg, mt * 16 + l4 * 4 + 2);
    float bq3 = __shfl(bvreg, mt * 16 + l4 * 4 + 3);
#pragma unroll
    for (int nt = 0; nt < 4; ++nt) {
      pk[mt][nt].x = (unsigned)f2bf(acc[mt][nt][0] + bq0) |
                     ((unsigned)f2bf(acc[mt][nt][1] + bq1) << 16);
      pk[mt][nt].y = (unsigned)f2bf(acc[mt][nt][2] + bq2) |
                     ((unsigned)f2bf(acc[mt][nt][3] + bq3) << 16);
    }
  }

  // ---- rank-1 softmax scalars (wave-local) ----
  float bmax = beta, bmin = beta;
#pragma unroll
  for (int o = 32; o >= 1; o >>= 1) {
    bmax = fmaxf(bmax, __shfl_xor(bmax, o));
    bmin = fminf(bmin, __shfl_xor(bmin, o));
  }
  float m = alpha >= 0.f ? alpha * bmax : alpha * bmin;
  float ssum = 0.f;
#pragma unroll 8
  for (int kk = 0; kk < 64; ++kk)
    ssum += __expf(fmaf(alpha, __shfl(beta, kk), -m));
  float inv = 1.0f / ssum;

  // ---- PV: D[m=qq][n=dd] = sum_kk P^T[qq][kk] * V^T[dd][kk] ----
  f32x4_t acc2[4][4];
#pragma unroll
  for (int i = 0; i < 4; ++i)
#pragma unroll
    for (int j = 0; j < 4; ++j) acc2[i][j] = (f32x4_t){0.f, 0.f, 0.f, 0.f};

  // B-fragment needs: lane(l15,l4) elem i -> V[kk = ks*32 + l4*8 + i][dd = nt2*16 + l15].
  // Source data: lane l' holds pk[mt][nt2] = V[kk = mt*16 + (l'>>4)*4 + {0..3}][dd = nt2*16 + (l'&15)].
  // -> mt_src = ks*2 + (l4>>1)  (DESTINATION-side), source lanes sib0/sib1 with
  //    l'>>4 = (l4&1)*2 + {0,1}, l'&15 = l15.
  // __shfl evaluates its operand in the SOURCE lane, so shuffle BOTH mt
  // candidates (uniform operand) and select with the destination's hi bit.
  const int sib0 = (l4 & 1) * 32 + l15;
  const int sib1 = sib0 + 16;
  const bool hi = (l4 >= 2);

#pragma unroll
  for (int ks = 0; ks < 2; ++ks) {
    // A-operand: P^T fragments, one per qq-tile mt2
    bf16x8_t pa[4];
    float bb[8];
#pragma unroll
    for (int i = 0; i < 8; ++i) bb[i] = __shfl(beta, ks * 32 + l4 * 8 + i);
#pragma unroll
    for (int mt2 = 0; mt2 < 4; ++mt2) {
      float aq = __shfl(alpha, mt2 * 16 + l15);
      float mq = __shfl(m, mt2 * 16 + l15);
      float iq = __shfl(inv, mt2 * 16 + l15);
      bf16x8_t pp;
#pragma unroll
      for (int i = 0; i < 8; ++i)
        pp[i] = (short)f2bf(__expf(fmaf(aq, bb[i], -mq)) * iq);
      pa[mt2] = pp;
    }
    // B-operand: V^T fragments per dd-tile nt2, dual-shfl + dest-side select
    bf16x8_t vb[4];
#pragma unroll
    for (int nt2 = 0; nt2 < 4; ++nt2) {
      unsigned lo_x0 = __shfl(pk[ks * 2][nt2].x, sib0);
      unsigned lo_y0 = __shfl(pk[ks * 2][nt2].y, sib0);
      unsigned lo_x1 = __shfl(pk[ks * 2][nt2].x, sib1);
      unsigned lo_y1 = __shfl(pk[ks * 2][nt2].y, sib1);
      unsigned hi_x0 = __shfl(pk[ks * 2 + 1][nt2].x, sib0);
      unsigned hi_y0 = __shfl(pk[ks * 2 + 1][nt2].y, sib0);
      unsigned hi_x1 = __shfl(pk[ks * 2 + 1][nt2].x, sib1);
      unsigned hi_y1 = __shfl(pk[ks * 2 + 1][nt2].y, sib1);
      uint4 q = make_uint4(hi ? hi_x0 : lo_x0, hi ? hi_y0 : lo_y0,
                           hi ? hi_x1 : lo_x1, hi ? hi_y1 : lo_y1);
      vb[nt2] = *(const bf16x8_t*)&q;
    }
#pragma unroll
    for (int mt2 = 0; mt2 < 4; ++mt2)
#pragma unroll
      for (int nt2 = 0; nt2 < 4; ++nt2)
        acc2[mt2][nt2] = __builtin_amdgcn_mfma_f32_16x16x32_bf16(
            pa[mt2], vb[nt2], acc2[mt2][nt2], 0, 0, 0);
  }

  // ---- stores: D[m=qq][n=dd]; lane = dd fixed, 4 consecutive qq -> float4 ----
  // acc2[mt2][nt2] reg r: qq = mt2*16 + l4*4 + r, dd = nt2*16 + l15.
#pragma unroll
  for (int nt2 = 0; nt2 < 4; ++nt2) {
    int dd = nt2 * 16 + l15;
    size_t base = (((size_t)(b * 512 + n * 64 + dd)) * 64 + (g * 8 + w)) * 64;
#pragma unroll
    for (int mt2 = 0; mt2 < 4; ++mt2) {
      float4 v = make_float4(acc2[mt2][nt2][0], acc2[mt2][nt2][1],
                             acc2[mt2][nt2][2], acc2[mt2][nt2][3]);
      *(float4*)(out + base + mt2 * 16 + l4 * 4) = v;
    }
  }
}

// ---------------------------------------------------------------------------
extern "C" void kernel_launch(void* const* d_in, const int* in_sizes, int n_in,
                              void* d_out, int out_size, void* d_ws, size_t ws_size,
                              hipStream_t stream) {
  const float* guide = (const float*)d_in[0];
  const float* hid   = (const float*)d_in[1];
  const float* Wq    = (const float*)d_in[2];
  const float* bq    = (const float*)d_in[3];
  const float* Wk    = (const float*)d_in[4];
  const float* bk    = (const float*)d_in[5];
  const float* Wv    = (const float*)d_in[6];
  const float* bv    = (const float*)d_in[7];
  float* out = (float*)d_out;

  char* ws = (char*)d_ws;
  unsigned short* XT  = (unsigned short*)(ws);             // 33,554,432 B
  unsigned short* Wvb = (unsigned short*)(ws + 33554432);  //    524,288 B
  float* hrsum        = (float*)(ws + 34078720);           //  1,048,576 B
  float* K2           = (float*)(ws + 35127296);           //  1,048,576 B
  float* qs           = (float*)(ws + 36175872);           //     16,384 B

  k_trans<<<528, 256, 0, stream>>>(hid, XT, hrsum, Wv, Wvb);
  k_k2<<<272, 256, 0, stream>>>(hrsum, Wk, bk, guide, Wq, bq, K2, qs);
  k_fused<<<512, 512, 0, stream>>>(XT, Wvb, K2, qs, bv, out);
}

// Round 7
// 94.702 us; speedup vs baseline: 1.0748x; 1.0748x over previous
//
#include <hip/hip_runtime.h>
#include <hip/hip_bf16.h>
#include <stdint.h>

// ---------------------------------------------------------------------------
// MultiHeadCrossAttention, B=8 C=512 H=W=64 nh=8 d=64.
// Index algebra (t = h*64+w, f = t*512+c):
//   n = h>>3 (the HEAD), dd = (h&7)*8 + (w>>3), hh = (w&7)*8 + (c>>6), ww = c&63
// With e = hh&7, g = hh>>3: token j within slab (b,n): j = 8*dd + g.
// q broadcast over tokens -> scores rank-1:
//   scores[qq,kk] = qs[b][e*64+qq] * K2[b,n,g][e*64+kk]
//   qs = (guide@Wq^T + bq)*0.125 ; K2 = hrsum@Wk^T + 64*bk
//   hrsum[b,n,g,c'] = sum_{j==g mod 8} hid[b,c',n*512+j]
// attended[qq,dd] = sum_kk softmax(scores)[qq,kk] * V[e*64+kk][j(dd,g)]
//   V[c][j] = sum_c' Wv[c][c'] * hid[b][c'][n*512+j] + bv[c]
// out[b][n*64+dd][g*8+e][qq]
//
// r7: REGISTER DIET. __launch_bounds__(512,4) caps unified VGPR+AGPR at 128;
// r4/r6 live sets (~180) spilled to scratch (VGPR_Count=64, WRITE_SIZE 75-102MB
// vs 64MB out). Never hold acc+acc2 together: K-loop (single af buf) -> barrier
// -> spill V into the DEAD X-tile LDS (wave slice) -> r4's proven LDS-va PV.
// k_trans: c'-half split (grid 1040, disjoint hrsum rows) + reg prefetch.
// ---------------------------------------------------------------------------

typedef __attribute__((ext_vector_type(8))) short bf16x8_t;
typedef __attribute__((ext_vector_type(4))) float f32x4_t;

__device__ __forceinline__ unsigned short f2bf(float f) {
  unsigned int u = __float_as_uint(f);
  u += 0x7FFFu + ((u >> 16) & 1u);
  return (unsigned short)(u >> 16);
}

__device__ __forceinline__ void gload16(const void* g, void* lds) {
  __builtin_amdgcn_global_load_lds(
      (const __attribute__((address_space(1))) unsigned int*)g,
      (__attribute__((address_space(3))) unsigned int*)lds, 16, 0, 0);
}

// ---------------- kernel 2: transpose hid -> XT (bf16) + hrsum (fp32) -------
// blocks [0,1024): (b,n,cb,rhalf) -> 32 c' rows x 512 j. [1024,1040): Wv cvt.
__global__ __launch_bounds__(256) void k_trans(const float* __restrict__ hid,
                                               unsigned short* __restrict__ XT,
                                               float* __restrict__ hrsum,
                                               const float* __restrict__ Wv,
                                               unsigned short* __restrict__ Wvb) {
  int bid = blockIdx.x;
  int tid = threadIdx.x;
  if (bid >= 1024) {
    int blk = bid - 1024;
#pragma unroll
    for (int i = 0; i < 16; ++i) {
      int idx = blk * 4096 + i * 256 + tid;
      float4 v = ((const float4*)Wv)[idx];
      ushort4 o;
      o.x = f2bf(v.x); o.y = f2bf(v.y); o.z = f2bf(v.z); o.w = f2bf(v.w);
      ((ushort4*)Wvb)[idx] = o;
    }
    return;
  }
  int rh = bid & 1, cb = (bid >> 1) & 7, n = (bid >> 4) & 7, b = bid >> 7;
  __shared__ float T[32][65];
  __shared__ float hsred[32][8];
  ((float*)hsred)[tid] = 0.f;

  float part[2][4];
#pragma unroll
  for (int m = 0; m < 2; ++m)
#pragma unroll
    for (int i = 0; i < 4; ++i) part[m][i] = 0.f;

  const int f4 = tid & 15;       // float4 index within 64-j chunk
  const int r0 = tid >> 4;       // local c' row group (0..15)
  const float* srcbase = hid + (size_t)(b * 512 + cb * 64 + rh * 32) * 4096 + n * 512;
  unsigned short* xtbase =
      XT + (size_t)(b * 8 + n) * 512 * 512 + cb * 64 + rh * 32;

  float4 va[2], vb2[2];
#pragma unroll
  for (int m = 0; m < 2; ++m)
    va[m] = *(const float4*)(srcbase + (size_t)(r0 + 16 * m) * 4096 + f4 * 4);

#define TSTEP(JC, CUR, NXT, LAST)                                              \
  do {                                                                         \
    _Pragma("unroll")                                                          \
    for (int m_ = 0; m_ < 2; ++m_) {                                           \
      int r_ = r0 + 16 * m_;                                                   \
      T[r_][f4 * 4 + 0] = CUR[m_].x;  T[r_][f4 * 4 + 1] = CUR[m_].y;           \
      T[r_][f4 * 4 + 2] = CUR[m_].z;  T[r_][f4 * 4 + 3] = CUR[m_].w;           \
      part[m_][0] += CUR[m_].x; part[m_][1] += CUR[m_].y;                      \
      part[m_][2] += CUR[m_].z; part[m_][3] += CUR[m_].w;                      \
    }                                                                          \
    if (!(LAST)) {                                                             \
      _Pragma("unroll")                                                        \
      for (int m_ = 0; m_ < 2; ++m_)                                           \
        NXT[m_] = *(const float4*)(srcbase + (size_t)(r0 + 16 * m_) * 4096 +   \
                                   ((JC) + 1) * 64 + f4 * 4);                  \
    }                                                                          \
    __syncthreads();                                                           \
    {                                                                          \
      int jl_ = tid >> 2, o_ = tid & 3;                                        \
      unsigned short t0 = f2bf(T[o_ * 8 + 0][jl_]);                            \
      unsigned short t1 = f2bf(T[o_ * 8 + 1][jl_]);                            \
      unsigned short t2 = f2bf(T[o_ * 8 + 2][jl_]);                            \
      unsigned short t3 = f2bf(T[o_ * 8 + 3][jl_]);                            \
      unsigned short t4 = f2bf(T[o_ * 8 + 4][jl_]);                            \
      unsigned short t5 = f2bf(T[o_ * 8 + 5][jl_]);                            \
      unsigned short t6 = f2bf(T[o_ * 8 + 6][jl_]);                            \
      unsigned short t7 = f2bf(T[o_ * 8 + 7][jl_]);                            \
      uint4 pk_;                                                               \
      pk_.x = (unsigned)t0 | ((unsigned)t1 << 16);                             \
      pk_.y = (unsigned)t2 | ((unsigned)t3 << 16);                             \
      pk_.z = (unsigned)t4 | ((unsigned)t5 << 16);                             \
      pk_.w = (unsigned)t6 | ((unsigned)t7 << 16);                             \
      *(uint4*)(xtbase + (size_t)((JC) * 64 + jl_) * 512 + o_ * 8) = pk_;      \
    }                                                                          \
    __syncthreads();                                                           \
  } while (0)

  TSTEP(0, va, vb2, 0);
  TSTEP(1, vb2, va, 0);
  TSTEP(2, va, vb2, 0);
  TSTEP(3, vb2, va, 0);
  TSTEP(4, va, vb2, 0);
  TSTEP(5, vb2, va, 0);
  TSTEP(6, va, vb2, 0);
  TSTEP(7, vb2, va, 1);
#undef TSTEP

  {
    int gbase = (f4 & 1) * 4;
#pragma unroll
    for (int m = 0; m < 2; ++m) {
      int r = r0 + 16 * m;
#pragma unroll
      for (int i = 0; i < 4; ++i) atomicAdd(&hsred[r][gbase + i], part[m][i]);
    }
  }
  __syncthreads();
  // disjoint rows: this block owns c' = cb*64 + rh*32 + [0,32)
  float* hout = hrsum + (size_t)(b * 8 + n) * 4096 + cb * 64 + rh * 32;
  {
    int g = tid >> 5, r = tid & 31;
    hout[(size_t)g * 512 + r] = hsred[r][g];
  }
}

// ---------------- kernel 3: K2 = hrsum@Wk^T + 64*bk ; qs = (guide@Wq^T+bq)/8 -
__global__ __launch_bounds__(256) void k_k2(const float* __restrict__ hrsum,
                                            const float* __restrict__ Wk,
                                            const float* __restrict__ bk,
                                            const float* __restrict__ guide,
                                            const float* __restrict__ Wq,
                                            const float* __restrict__ bq,
                                            float* __restrict__ K2,
                                            float* __restrict__ qs) {
  int bid = blockIdx.x;
  int rt = bid >> 4, ct = bid & 15;
  bool isQ = (rt == 16);
  const float* A = isQ ? guide : (hrsum + (size_t)rt * 32 * 512);
  const float* Bm = isQ ? Wq : Wk;
  int arows = isQ ? 8 : 32;
  int tid = threadIdx.x;
  __shared__ float Ah[32][36];
  __shared__ float Bh[32][36];
  int r = tid >> 3, f = tid & 7;
  int oy = (tid >> 4) * 2, ox = (tid & 15) * 2;
  float a00 = 0.f, a01 = 0.f, a10 = 0.f, a11 = 0.f;

  for (int kc = 0; kc < 16; ++kc) {
    __syncthreads();
    float4 av = (r < arows) ? *(const float4*)(A + (size_t)r * 512 + kc * 32 + f * 4)
                            : make_float4(0.f, 0.f, 0.f, 0.f);
    *(float4*)(&Ah[r][f * 4]) = av;
    float4 bv = *(const float4*)(Bm + (size_t)(ct * 32 + r) * 512 + kc * 32 + f * 4);
    *(float4*)(&Bh[r][f * 4]) = bv;
    __syncthreads();
#pragma unroll
    for (int kk = 0; kk < 32; kk += 4) {
      float4 x0 = *(float4*)(&Ah[oy][kk]);
      float4 x1 = *(float4*)(&Ah[oy + 1][kk]);
      float4 y0 = *(float4*)(&Bh[ox][kk]);
      float4 y1 = *(float4*)(&Bh[ox + 1][kk]);
      a00 += x0.x * y0.x + x0.y * y0.y + x0.z * y0.z + x0.w * y0.w;
      a01 += x0.x * y1.x + x0.y * y1.y + x0.z * y1.z + x0.w * y1.w;
      a10 += x1.x * y0.x + x1.y * y0.y + x1.z * y0.z + x1.w * y0.w;
      a11 += x1.x * y1.x + x1.y * y1.y + x1.z * y1.z + x1.w * y1.w;
    }
  }
  int c0 = ct * 32 + ox;
  if (!isQ) {
    int row0 = rt * 32 + oy;
    K2[(size_t)row0 * 512 + c0]           = a00 + 64.f * bk[c0];
    K2[(size_t)row0 * 512 + c0 + 1]       = a01 + 64.f * bk[c0 + 1];
    K2[(size_t)(row0 + 1) * 512 + c0]     = a10 + 64.f * bk[c0];
    K2[(size_t)(row0 + 1) * 512 + c0 + 1] = a11 + 64.f * bk[c0 + 1];
  } else if (oy < 8) {
    const float scale = 0.125f;
    qs[(size_t)oy * 512 + c0]           = (a00 + bq[c0]) * scale;
    qs[(size_t)oy * 512 + c0 + 1]       = (a01 + bq[c0 + 1]) * scale;
    qs[(size_t)(oy + 1) * 512 + c0]     = (a10 + bq[c0]) * scale;
    qs[(size_t)(oy + 1) * 512 + c0 + 1] = (a11 + bq[c0 + 1]) * scale;
  }
}

// ---------------- kernel 4: fused V-GEMM + rank-1 softmax + PV ---------------
// grid 512 = slab(64) * g(8), XCD-grouped; 512 threads = 8 waves, wave w = e.
// LDS 64KB: X-tile [8 kc][64 j][128B] during GEMM; overlaid per-wave V slices
// (w*8192) afterwards. Register diet: acc and acc2 never co-live; single af.
__global__ __launch_bounds__(512, 4) void k_fused(
    const unsigned short* __restrict__ XT, const unsigned short* __restrict__ Wvb,
    const float* __restrict__ K2, const float* __restrict__ qs,
    const float* __restrict__ bv, float* __restrict__ out) {
  int p = blockIdx.x;
  int xcd = p & 7, idx = p >> 3;
  int slab = xcd * 8 + (idx & 7);
  int g = idx >> 3;
  int n = slab & 7, b = slab >> 3;

  int tid = threadIdx.x;
  int w = tid >> 6, l = tid & 63;
  int l15 = l & 15, l4 = l >> 4, lr = l >> 3, lc = l & 7;

  __shared__ __align__(16) unsigned char smem[65536];

  const unsigned swzel = (unsigned)((lc ^ lr) << 3);  // pre-swizzled src col
  const unsigned short* bsrc = XT + (size_t)slab * 512 * 512;
  const unsigned short* wbase = Wvb + (size_t)(w * 64 + l15) * 512 + l4 * 8;
  const int brow = 8 * (w * 8 + lr) + g;

  // ---- stage B once: 8 x global_load_lds (16B) per thread ----
#pragma unroll
  for (int i = 0; i < 8; ++i)
    gload16(bsrc + (size_t)brow * 512 + i * 64 + swzel, smem + i * 8192 + w * 1024);

  float alpha = qs[(size_t)b * 512 + w * 64 + l];              // lane = qq
  float beta  = K2[(size_t)(slab * 8 + g) * 512 + w * 64 + l]; // lane = kk
  float bvreg = bv[w * 64 + l];                                // lane = kk

  f32x4_t acc[4][4];
#pragma unroll
  for (int i = 0; i < 4; ++i)
#pragma unroll
    for (int j = 0; j < 4; ++j) acc[i][j] = (f32x4_t){0.f, 0.f, 0.f, 0.f};

  __syncthreads();   // B resident for the whole K-loop

  // ---- barrier-free K-loop: 16 K32-steps, single af buffer ----
#pragma unroll
  for (int s = 0; s < 16; ++s) {
    bf16x8_t af[4];
#pragma unroll
    for (int mt = 0; mt < 4; ++mt)
      af[mt] = *(const bf16x8_t*)(wbase + mt * 16 * 512 + s * 32);
    unsigned char* Bb = smem + (s >> 1) * 8192;
    bf16x8_t bfr[4];
#pragma unroll
    for (int nt = 0; nt < 4; ++nt) {
      unsigned row = (unsigned)(nt * 16 + l15);
      bfr[nt] = *(const bf16x8_t*)(Bb + row * 128 +
                ((unsigned)((s & 1) * 64 + l4 * 16) ^ ((row & 7) << 4)));
    }
    __builtin_amdgcn_s_setprio(1);
#pragma unroll
    for (int mt = 0; mt < 4; ++mt)
#pragma unroll
      for (int nt = 0; nt < 4; ++nt)
        acc[mt][nt] = __builtin_amdgcn_mfma_f32_16x16x32_bf16(
            af[mt], bfr[nt], acc[mt][nt], 0, 0, 0);
    __builtin_amdgcn_s_setprio(0);
  }

  __syncthreads();   // all waves done reading the X-tile; safe to overlay

  // ---- spill V + bias -> wave-private Vp[dd][kk] bf16 (XOR-swizzled) ----
  // acc[mt][nt] reg r: kk = mt*16 + l4*4 + r, dd = nt*16 + l15.
  unsigned char* Vp = smem + w * 8192;
#pragma unroll
  for (int mt = 0; mt < 4; ++mt) {
    float bq0 = __shfl(bvreg, mt * 16 + l4 * 4 + 0);
    float bq1 = __shfl(bvreg, mt * 16 + l4 * 4 + 1);
    float bq2 = __shfl(bvreg, mt * 16 + l4 * 4 + 2);
    float bq3 = __shfl(bvreg, mt * 16 + l4 * 4 + 3);
#pragma unroll
    for (int nt = 0; nt < 4; ++nt) {
      unsigned dd = (unsigned)(nt * 16 + l15);
      uint2 pk;
      pk.x = (unsigned)f2bf(acc[mt][nt][0] + bq0) |
             ((unsigned)f2bf(acc[mt][nt][1] + bq1) << 16);
      pk.y = (unsigned)f2bf(acc[mt][nt][2] + bq2) |
             ((unsigned)f2bf(acc[mt][nt][3] + bq3) << 16);
      *(uint2*)(Vp + dd * 128 +
                ((unsigned)(mt * 32 + l4 * 8) ^ ((dd & 7) << 4))) = pk;
    }
  }

  // ---- phase 2: rank-1 softmax in-register + PV (wave-local, no barrier) ----
  float bmax = beta, bmin = beta;
#pragma unroll
  for (int o = 32; o >= 1; o >>= 1) {
    bmax = fmaxf(bmax, __shfl_xor(bmax, o));
    bmin = fminf(bmin, __shfl_xor(bmin, o));
  }
  float m = alpha >= 0.f ? alpha * bmax : alpha * bmin;
  float ssum = 0.f;
#pragma unroll 8
  for (int kk = 0; kk < 64; ++kk)
    ssum += __expf(fmaf(alpha, __shfl(beta, kk), -m));
  float inv = 1.0f / ssum;

  f32x4_t acc2[4][4];
#pragma unroll
  for (int i = 0; i < 4; ++i)
#pragma unroll
    for (int j = 0; j < 4; ++j) acc2[i][j] = (f32x4_t){0.f, 0.f, 0.f, 0.f};

#pragma unroll
  for (int ks = 0; ks < 2; ++ks) {
    bf16x8_t va[4];
#pragma unroll
    for (int mt = 0; mt < 4; ++mt) {   // A[dd][kk] from Vp
      unsigned dd = (unsigned)(mt * 16 + l15);
      va[mt] = *(const bf16x8_t*)(Vp + dd * 128 +
                ((unsigned)(ks * 64 + l4 * 16) ^ ((dd & 7) << 4)));
    }
    float bvv[8];
#pragma unroll
    for (int i = 0; i < 8; ++i) bvv[i] = __shfl(beta, ks * 32 + l4 * 8 + i);
    bf16x8_t pb[4];
#pragma unroll
    for (int nt = 0; nt < 4; ++nt) {   // B[kk][qq] built in registers
      int qq = nt * 16 + l15;
      float aq = __shfl(alpha, qq);
      float mq = __shfl(m, qq);
      float iq = __shfl(inv, qq);
      bf16x8_t pp;
#pragma unroll
      for (int i = 0; i < 8; ++i)
        pp[i] = (short)f2bf(__expf(fmaf(aq, bvv[i], -mq)) * iq);
      pb[nt] = pp;
    }
#pragma unroll
    for (int mt = 0; mt < 4; ++mt)
#pragma unroll
      for (int nt = 0; nt < 4; ++nt)
        acc2[mt][nt] = __builtin_amdgcn_mfma_f32_16x16x32_bf16(
            va[mt], pb[nt], acc2[mt][nt], 0, 0, 0);
  }

  // ---- stores: D[m=dd][n=qq], contiguous 64B per 16 lanes ----
#pragma unroll
  for (int mt = 0; mt < 4; ++mt) {
#pragma unroll
    for (int r = 0; r < 4; ++r) {
      int dd = mt * 16 + l4 * 4 + r;
      size_t base = (((size_t)(b * 512 + n * 64 + dd)) * 64 + (g * 8 + w)) * 64;
#pragma unroll
      for (int nt = 0; nt < 4; ++nt)
        out[base + nt * 16 + l15] = acc2[mt][nt][r];
    }
  }
}

// ---------------------------------------------------------------------------
extern "C" void kernel_launch(void* const* d_in, const int* in_sizes, int n_in,
                              void* d_out, int out_size, void* d_ws, size_t ws_size,
                              hipStream_t stream) {
  const float* guide = (const float*)d_in[0];
  const float* hid   = (const float*)d_in[1];
  const float* Wq    = (const float*)d_in[2];
  const float* bq    = (const float*)d_in[3];
  const float* Wk    = (const float*)d_in[4];
  const float* bk    = (const float*)d_in[5];
  const float* Wv    = (const float*)d_in[6];
  const float* bv    = (const float*)d_in[7];
  float* out = (float*)d_out;

  char* ws = (char*)d_ws;
  unsigned short* XT  = (unsigned short*)(ws);             // 33,554,432 B
  unsigned short* Wvb = (unsigned short*)(ws + 33554432);  //    524,288 B
  float* hrsum        = (float*)(ws + 34078720);           //  1,048,576 B
  float* K2           = (float*)(ws + 35127296);           //  1,048,576 B
  float* qs           = (float*)(ws + 36175872);           //     16,384 B

  k_trans<<<1040, 256, 0, stream>>>(hid, XT, hrsum, Wv, Wvb);
  k_k2<<<272, 256, 0, stream>>>(hrsum, Wk, bk, guide, Wq, bq, K2, qs);
  k_fused<<<512, 512, 0, stream>>>(XT, Wvb, K2, qs, bv, out);
}